// Round 3
// baseline (3967.333 us; speedup 1.0000x reference)
//
#include <hip/hip_runtime.h>
#include <math.h>

#define NB   4096
#define NIN  768
#define NLAT 24576
#define K2   1536   // [Ah|Al] x [Bh|Bh]
#define KT2  24     // K2/64

// f32 fallback GEMM tiling
#define BM 128
#define BN 128
#define BK 16
#define LDT 132

#define CAND_CAP 160
#define BAND_CAP 160
#define MAIN_CAP 64
#define AUX_CAP  1024
#define EPT      96
#define GROUPS   24

typedef __bf16 bf16x8 __attribute__((ext_vector_type(8)));
typedef float  f32x4  __attribute__((ext_vector_type(4)));

__device__ __forceinline__ unsigned fkey(float f) {
  unsigned u = __float_as_uint(f);
  return u ^ ((unsigned)((int)u >> 31) | 0x80000000u);  // monotone total order
}
__device__ __forceinline__ float keyinv(unsigned u) {
  unsigned s = (u & 0x80000000u) ? (u ^ 0x80000000u) : ~u;
  return __uint_as_float(s);
}

#define GLOAD16(g, l) __builtin_amdgcn_global_load_lds( \
    (const __attribute__((address_space(1))) unsigned int*)(g), \
    (__attribute__((address_space(3))) unsigned int*)(l), 16, 0, 0)

// ---------------- dead bitset: bit j = (miss[j] >= 1) ----------------
__global__ __launch_bounds__(256) void k_deadbits(const int* __restrict__ miss,
                                                  unsigned* __restrict__ bits) {
  int j = blockIdx.x * 256 + threadIdx.x;
  unsigned long long b = __ballot(miss[j] >= 1);
  if ((threadIdx.x & 63) == 0) {
    int w = j >> 5;
    bits[w] = (unsigned)b;
    bits[w + 1] = (unsigned)(b >> 32);
  }
}

// ---------------- W_dec [NIN][NLAT] -> Wt [NLAT][NIN] (bf16) ----------------
__global__ __launch_bounds__(256) void k_transpose(const float* __restrict__ src,
                                                   __bf16* __restrict__ dst) {
  __shared__ float tile[32][33];
  int bx = blockIdx.x * 32;  // NLAT
  int by = blockIdx.y * 32;  // NIN
  int tx = threadIdx.x, ty = threadIdx.y;
  for (int i = ty; i < 32; i += 8)
    tile[i][tx] = src[(size_t)(by + i) * NLAT + bx + tx];
  __syncthreads();
  for (int i = ty; i < 32; i += 8)
    dst[(size_t)(bx + i) * NIN + by + tx] = (__bf16)tile[tx][i];
}

// ---- pack (x-b) into A2 tiles [mt][kt][128][64], pre-swizzled LDS image ----
__global__ __launch_bounds__(256) void k_pack_a(const float* __restrict__ x,
    const float* __restrict__ bvec, __bf16* __restrict__ A2) {
  const int mt = blockIdx.x, kt = blockIdx.y, t = threadIdx.x;
  __bf16* out = A2 + (((size_t)mt * KT2 + kt) << 13);
#pragma unroll
  for (int i = 0; i < 32; ++i) {
    int idx = i * 256 + t;
    int r = idx >> 6, c2 = idx & 63;
    int kk = c2 ^ ((r & 7) << 3);
    int kg = kt * 64 + kk;
    int k = kg >= 768 ? kg - 768 : kg;
    bool lo = (kg >= 768);                            // A = [Ah | Al]
    float v = x[(size_t)(mt * 128 + r) * NIN + k] - bvec[k];
    __bf16 h = (__bf16)v;
    out[idx] = lo ? (__bf16)(v - (float)h) : h;
  }
}

__global__ __launch_bounds__(256) void k_pack_b(const float* __restrict__ We,
    __bf16* __restrict__ B2) {
  const int nt = blockIdx.x, kt = blockIdx.y, t = threadIdx.x;
  __bf16* out = B2 + (((size_t)nt * KT2 + kt) << 13);
#pragma unroll
  for (int i = 0; i < 32; ++i) {
    int idx = i * 256 + t;
    int r = idx >> 6, c2 = idx & 63;
    int kk = c2 ^ ((r & 7) << 3);
    int kg = kt * 64 + kk;
    int k = kg >= 768 ? kg - 768 : kg;                // B = [Bh | Bh]
    float v = We[(size_t)(nt * 128 + r) * NIN + k];
    out[idx] = (__bf16)v;
  }
}

// ---------------- bf16 MFMA GEMM: apre = A2 @ B2^T + be ----------------
__global__ __launch_bounds__(256) void k_gemm_bf16(
    const __bf16* __restrict__ A2, const __bf16* __restrict__ B2,
    const float* __restrict__ be, float* __restrict__ apre) {
  __shared__ char sA[16384];
  __shared__ char sB[16384];
  const int t = threadIdx.x;
  const int lane = t & 63, wave = t >> 6;
  const int mt = blockIdx.x, nt = blockIdx.y;
  const int wm = wave >> 1, wn = wave & 1;

  int aoff[4][2], boff[4][2];
#pragma unroll
  for (int f = 0; f < 4; ++f) {
    int ra = wm * 64 + f * 16 + (lane & 15);
    int rb = wn * 64 + f * 16 + (lane & 15);
#pragma unroll
    for (int kk = 0; kk < 2; ++kk) {
      int c = kk * 64 + (lane >> 4) * 16;
      aoff[f][kk] = ra * 128 + (c ^ ((ra & 7) << 4));
      boff[f][kk] = rb * 128 + (c ^ ((rb & 7) << 4));
    }
  }
  f32x4 acc[4][4] = {};
  const char* gA = (const char*)(A2 + (((size_t)mt * KT2) << 13));
  const char* gB = (const char*)(B2 + (((size_t)nt * KT2) << 13));
  for (int kt = 0; kt < KT2; ++kt) {
    const char* tA = gA + ((size_t)kt << 14);
    const char* tB = gB + ((size_t)kt << 14);
#pragma unroll
    for (int i = 0; i < 4; ++i) {
      int chunk = (i * 4 + wave) * 1024;
      GLOAD16(tA + chunk + lane * 16, sA + chunk);
      GLOAD16(tB + chunk + lane * 16, sB + chunk);
    }
    __syncthreads();
#pragma unroll
    for (int kk = 0; kk < 2; ++kk) {
      bf16x8 a[4], b[4];
#pragma unroll
      for (int f = 0; f < 4; ++f) {
        a[f] = *(const bf16x8*)(sA + aoff[f][kk]);
        b[f] = *(const bf16x8*)(sB + boff[f][kk]);
      }
#pragma unroll
      for (int mi = 0; mi < 4; ++mi)
#pragma unroll
        for (int ni = 0; ni < 4; ++ni)
          acc[mi][ni] = __builtin_amdgcn_mfma_f32_16x16x32_bf16(a[mi], b[ni], acc[mi][ni], 0, 0, 0);
    }
    __syncthreads();
  }
  const int m0 = mt * 128 + wm * 64, n0 = nt * 128 + wn * 64;
#pragma unroll
  for (int ni = 0; ni < 4; ++ni) {
    int n = n0 + ni * 16 + (lane & 15);
    float bb = be[n];
#pragma unroll
    for (int mi = 0; mi < 4; ++mi) {
      int mbase = m0 + mi * 16 + (lane >> 4) * 4;
#pragma unroll
      for (int q = 0; q < 4; ++q)
        apre[(size_t)(mbase + q) * NLAT + n] = acc[mi][ni][q] + bb;
    }
  }
}

// ---------------- f32 fallback GEMM ----------------
__global__ __launch_bounds__(256) void k_encgemm_f32(
    const float* __restrict__ x, const float* __restrict__ bvec,
    const float* __restrict__ We, const float* __restrict__ be,
    float* __restrict__ apre) {
  __shared__ float As[BK][LDT];
  __shared__ float Bs[BK][LDT];
  const int t = threadIdx.x;
  const int m0 = blockIdx.x * BM;
  const int n0 = blockIdx.y * BN;
  const int lane = t & 63, wave = t >> 6;
  const int cn = ((wave & 1) * 8 + (lane & 7)) * 8;
  const int cm = ((wave >> 1) * 8 + (lane >> 3)) * 8;
  float acc[8][8] = {};
  const float* xb = x + (size_t)m0 * NIN;
  const float* wb = We + (size_t)n0 * NIN;
  for (int k0 = 0; k0 < NIN; k0 += BK) {
#pragma unroll
    for (int i = 0; i < 2; ++i) {
      int e = t + i * 256;
      int row = e >> 2, q = e & 3;
      float4 bv = *(const float4*)(bvec + k0 + q * 4);
      float4 av = *(const float4*)(xb + (size_t)row * NIN + k0 + q * 4);
      av.x -= bv.x; av.y -= bv.y; av.z -= bv.z; av.w -= bv.w;
      As[q * 4 + 0][row] = av.x; As[q * 4 + 1][row] = av.y;
      As[q * 4 + 2][row] = av.z; As[q * 4 + 3][row] = av.w;
      float4 wv = *(const float4*)(wb + (size_t)row * NIN + k0 + q * 4);
      Bs[q * 4 + 0][row] = wv.x; Bs[q * 4 + 1][row] = wv.y;
      Bs[q * 4 + 2][row] = wv.z; Bs[q * 4 + 3][row] = wv.w;
    }
    __syncthreads();
#pragma unroll
    for (int kk = 0; kk < BK; ++kk) {
      float a0[8], b0[8];
      *(float4*)&a0[0] = *(const float4*)&As[kk][cm];
      *(float4*)&a0[4] = *(const float4*)&As[kk][cm + 4];
      *(float4*)&b0[0] = *(const float4*)&Bs[kk][cn];
      *(float4*)&b0[4] = *(const float4*)&Bs[kk][cn + 4];
#pragma unroll
      for (int i = 0; i < 8; ++i)
#pragma unroll
        for (int j = 0; j < 8; ++j)
          acc[i][j] = fmaf(a0[i], b0[j], acc[i][j]);
    }
    __syncthreads();
  }
  float bb[8];
  *(float4*)&bb[0] = *(const float4*)(be + n0 + cn);
  *(float4*)&bb[4] = *(const float4*)(be + n0 + cn + 4);
#pragma unroll
  for (int i = 0; i < 8; ++i) {
    float4 v0 = make_float4(acc[i][0] + bb[0], acc[i][1] + bb[1],
                            acc[i][2] + bb[2], acc[i][3] + bb[3]);
    float4 v1 = make_float4(acc[i][4] + bb[4], acc[i][5] + bb[5],
                            acc[i][6] + bb[6], acc[i][7] + bb[7]);
    float* orow = apre + (size_t)(m0 + cm + i) * NLAT + n0 + cn;
    *(float4*)orow = v0;
    *(float4*)(orow + 4) = v1;
  }
}

// ------------- per-row: register-resident bisection top-k + decode ----
// NOTE: apre and mask alias (mask overwrites the alpha_pre scratch) — no
// __restrict__ on either. Each block touches only its own row for both.
__global__ __launch_bounds__(256, 3) void k_select2(
    const float* apre, const float* __restrict__ x,
    const float* __restrict__ bvec, const float* __restrict__ We,
    const float* __restrict__ be, const unsigned* __restrict__ dbits,
    const int* __restrict__ kptr, const int* __restrict__ akptr,
    float* __restrict__ alpha, float* mask,
    float* __restrict__ xhat, float* __restrict__ auxo,
    const __bf16* __restrict__ Wt, const float* __restrict__ Wd) {
  const int t = threadIdx.x;
  const int r = blockIdx.x;
  const int lane = t & 63, wave = t >> 6;

  __shared__ int wsum[2][4];
  __shared__ int ctrl[8];
  __shared__ unsigned candK[CAND_CAP];
  __shared__ int candI[CAND_CAP];
  __shared__ int bandI[BAND_CAP];
  __shared__ double bandV[BAND_CAP];
  __shared__ unsigned char bandSel[BAND_CAP];
  __shared__ int mIdx[MAIN_CAP];
  __shared__ float mVal[MAIN_CAP];
  __shared__ int aIdx[AUX_CAP];
  __shared__ float aVal[AUX_CAP];

  // ---- load row as sort keys (96 regs) ----
  unsigned key[EPT];
  const float4* rowp = (const float4*)(apre + (size_t)r * NLAT);
#pragma unroll
  for (int i = 0; i < GROUPS; ++i) {
    float4 v = rowp[t + 256 * i];
    key[4 * i + 0] = fkey(v.x); key[4 * i + 1] = fkey(v.y);
    key[4 * i + 2] = fkey(v.z); key[4 * i + 3] = fkey(v.w);
  }
  // ---- dead nibbles: dm bits e -> element 4i+q dead ----
  unsigned dm0 = 0, dm1 = 0, dm2 = 0;
#pragma unroll
  for (int i = 0; i < GROUPS; ++i) {
    unsigned w = dbits[(t + 256 * i) >> 3];
    unsigned nb = (w >> ((t & 7) * 4)) & 0xFu;
    if (i < 8) dm0 |= nb << (i * 4);
    else if (i < 16) dm1 |= nb << ((i - 8) * 4);
    else dm2 |= nb << ((i - 16) * 4);
  }
  int kmain = kptr[0]; if (kmain > MAIN_CAP) kmain = MAIN_CAP;
  int kaux  = akptr[0]; if (kaux > AUX_CAP)  kaux  = AUX_CAP;

  int parity = 0;
  auto blockCountGE = [&](unsigned T) -> int {
    int c = 0;
#pragma unroll
    for (int e = 0; e < EPT; ++e) c += (key[e] >= T) ? 1 : 0;
#pragma unroll
    for (int o = 32; o; o >>= 1) c += __shfl_xor(c, o);
    if (lane == 0) wsum[parity][wave] = c;
    __syncthreads();
    int s = wsum[parity][0] + wsum[parity][1] + wsum[parity][2] + wsum[parity][3];
    parity ^= 1;
    return s;
  };

  int kcMain = 0, acAux = 0;
  for (int pass = 0; pass < 2; ++pass) {
    int kreq, nelig;
    if (pass == 0) { kreq = kmain; nelig = NLAT; }
    else {
      // zero non-dead keys (alpha/mask already written); key 0 can't be selected
#pragma unroll
      for (int e = 0; e < EPT; ++e) {
        int i = e >> 2, q = e & 3;
        unsigned m = (i < 8) ? dm0 : ((i < 16) ? dm1 : dm2);
        unsigned bit = (m >> (((i & 7) << 2) | q)) & 1u;
        if (!bit) key[e] = 0u;
      }
      int pc = __popc(dm0) + __popc(dm1) + __popc(dm2);
#pragma unroll
      for (int o = 32; o; o >>= 1) pc += __shfl_xor(pc, o);
      if (lane == 0) wsum[parity][wave] = pc;
      __syncthreads();
      nelig = wsum[parity][0] + wsum[parity][1] + wsum[parity][2] + wsum[parity][3];
      parity ^= 1;
      kreq = kaux;
    }
    if (kreq > nelig) kreq = nelig;
    if (kreq <= 0) {
      if (t == 0) ctrl[4] = 0;
      __syncthreads();
      if (pass == 1) acAux = 0;
      continue;
    }

    // ---- bisection on key space ----
    unsigned Tlo = 0u, Thi = 0xFFFFFFFFu;
    int cLo = nelig;
    int cHi = blockCountGE(0xFFFFFFFFu);
    if (cHi >= kreq) cHi = kreq - 1;  // degenerate guard (NaN flood)
    while ((cLo - cHi) > (CAND_CAP - 8) && (Thi - Tlo) > 1u) {
      unsigned T = Tlo + ((Thi - Tlo) >> 1);
      int c = blockCountGE(T);
      if (c >= kreq) { Tlo = T; cLo = c; } else { Thi = T; cHi = c; }
    }

    // ---- extract window candidates, exact-rank the k-th key ----
    if (t == 0) ctrl[0] = 0;
    __syncthreads();
#pragma unroll
    for (int i = 0; i < GROUPS; ++i)
#pragma unroll
      for (int q = 0; q < 4; ++q) {
        unsigned kk = key[4 * i + q];
        if (kk >= Tlo && kk < Thi) {
          int p = atomicAdd(&ctrl[0], 1);
          if (p < CAND_CAP) { candK[p] = kk; candI[p] = 4 * (t + 256 * i) + q; }
        }
      }
    __syncthreads();
    int cc = ctrl[0]; if (cc > CAND_CAP) cc = CAND_CAP;
    int need = kreq - cHi;
    if (need < 1) need = 1;
    if (need > cc) need = cc;
    if (t < cc) {
      unsigned ki = candK[t]; int ii = candI[t];
      int rank = 0;
      for (int qq = 0; qq < cc; ++qq) {
        unsigned kq = candK[qq];
        rank += (kq > ki || (kq == ki && candI[qq] < ii)) ? 1 : 0;
      }
      if (rank == need - 1) ctrl[1] = (int)ki;
    }
    __syncthreads();

    // ---- f64 band refinement around V* ----
    unsigned Kstar = (unsigned)ctrl[1];
    float Vs = keyinv(Kstar);
    float eps = 1e-2f + 2e-3f * fabsf(Vs);
    unsigned KhiB = fkey(Vs + eps), KloB = fkey(Vs - eps);
    if (t == 0) { ctrl[2] = 0; ctrl[3] = 0; }
    __syncthreads();
    int abv = 0;
#pragma unroll
    for (int i = 0; i < GROUPS; ++i)
#pragma unroll
      for (int q = 0; q < 4; ++q) {
        unsigned kk = key[4 * i + q];
        if (kk > KhiB) ++abv;
        else if (kk >= KloB) {
          int p = atomicAdd(&ctrl[3], 1);
          if (p < BAND_CAP) bandI[p] = 4 * (t + 256 * i) + q;
        }
      }
#pragma unroll
    for (int o = 32; o; o >>= 1) abv += __shfl_xor(abv, o);
    if (lane == 0) atomicAdd(&ctrl[2], abv);
    __syncthreads();
    int nAb = ctrl[2];
    int bc = ctrl[3]; if (bc > BAND_CAP) bc = BAND_CAP;
    int needB = kreq - nAb;
    if (needB < 0) needB = 0;
    if (needB > bc) needB = bc;

    if (t < bc) {
      int j = bandI[t];
      const float* wr = We + (size_t)j * NIN;
      const float* xr = x + (size_t)r * NIN;
      double s0 = 0.0, s1 = 0.0, s2 = 0.0, s3 = 0.0;
      for (int kx = 0; kx < NIN; kx += 4) {
        s0 += ((double)xr[kx]     - (double)bvec[kx])     * (double)wr[kx];
        s1 += ((double)xr[kx + 1] - (double)bvec[kx + 1]) * (double)wr[kx + 1];
        s2 += ((double)xr[kx + 2] - (double)bvec[kx + 2]) * (double)wr[kx + 2];
        s3 += ((double)xr[kx + 3] - (double)bvec[kx + 3]) * (double)wr[kx + 3];
      }
      bandV[t] = ((s0 + s1) + (s2 + s3)) + (double)be[j];
    }
    __syncthreads();
    if (t < bc) {
      double vi = bandV[t]; int ii = bandI[t];
      double tie = fabs(vi) * 4e-8 + 1e-12;
      int rank = 0;
      for (int qq = 0; qq < bc; ++qq) {
        double d = bandV[qq] - vi;
        rank += ((fabs(d) <= tie) ? (bandI[qq] < ii) : (d > 0.0)) ? 1 : 0;
      }
      bandSel[t] = (rank < needB) ? 1 : 0;
    }
    if (t == 0) ctrl[4] = 0;
    __syncthreads();

    // ---- emit ----
    if (pass == 0) {
      float4* arow = (float4*)(alpha + (size_t)r * NLAT);
      float4* mrow = (float4*)(mask + (size_t)r * NLAT);
#pragma unroll
      for (int i = 0; i < GROUPS; ++i) {
        float av[4], mv[4];
#pragma unroll
        for (int q = 0; q < 4; ++q) {
          unsigned kk = key[4 * i + q];
          int j = 4 * (t + 256 * i) + q;
          bool sel = kk > KhiB;
          if (!sel && kk >= KloB) {
            for (int m2 = 0; m2 < bc; ++m2)
              if (bandI[m2] == j) { sel = bandSel[m2] != 0; break; }
          }
          float v = keyinv(kk);
          bool nz = sel && (v != 0.0f);
          av[q] = sel ? v : 0.0f;
          mv[q] = nz ? 1.0f : 0.0f;
          if (nz) {
            int p = atomicAdd(&ctrl[4], 1);
            if (p < MAIN_CAP) { mIdx[p] = j; mVal[p] = v; }
          }
        }
        arow[t + 256 * i] = make_float4(av[0], av[1], av[2], av[3]);
        mrow[t + 256 * i] = make_float4(mv[0], mv[1], mv[2], mv[3]);
      }
    } else {
#pragma unroll
      for (int i = 0; i < GROUPS; ++i)
#pragma unroll
        for (int q = 0; q < 4; ++q) {
          unsigned kk = key[4 * i + q];
          if (kk == 0u) continue;  // masked-out (non-dead)
          int j = 4 * (t + 256 * i) + q;
          bool sel = kk > KhiB;
          if (!sel && kk >= KloB) {
            for (int m2 = 0; m2 < bc; ++m2)
              if (bandI[m2] == j) { sel = bandSel[m2] != 0; break; }
          }
          float v = keyinv(kk);
          if (sel && v != 0.0f) {
            int p = atomicAdd(&ctrl[4], 1);
            if (p < AUX_CAP) { aIdx[p] = j; aVal[p] = v; }
          }
        }
    }
    __syncthreads();
    if (pass == 0) kcMain = ctrl[4] < MAIN_CAP ? ctrl[4] : MAIN_CAP;
    else           acAux  = ctrl[4] < AUX_CAP  ? ctrl[4] : AUX_CAP;
    __syncthreads();
  }

  // ---- decode ----
  int kc = kcMain, ac = acAux;
  float o0 = 0.f, o1 = 0.f, o2 = 0.f, a0 = 0.f, a1 = 0.f, a2 = 0.f;
  if (Wt) {
    for (int i = 0; i < kc; ++i) {
      float v = mVal[i];
      const __bf16* wr = Wt + (size_t)mIdx[i] * NIN;
      o0 = fmaf(v, (float)wr[t], o0);
      o1 = fmaf(v, (float)wr[t + 256], o1);
      o2 = fmaf(v, (float)wr[t + 512], o2);
    }
#pragma unroll 2
    for (int i = 0; i < ac; ++i) {
      float v = aVal[i];
      const __bf16* wr = Wt + (size_t)aIdx[i] * NIN;
      a0 = fmaf(v, (float)wr[t], a0);
      a1 = fmaf(v, (float)wr[t + 256], a1);
      a2 = fmaf(v, (float)wr[t + 512], a2);
    }
  } else {
    for (int i = 0; i < kc; ++i) {
      float v = mVal[i]; int ix = mIdx[i];
      o0 = fmaf(v, Wd[(size_t)t * NLAT + ix], o0);
      o1 = fmaf(v, Wd[(size_t)(t + 256) * NLAT + ix], o1);
      o2 = fmaf(v, Wd[(size_t)(t + 512) * NLAT + ix], o2);
    }
    for (int i = 0; i < ac; ++i) {
      float v = aVal[i]; int ix = aIdx[i];
      a0 = fmaf(v, Wd[(size_t)t * NLAT + ix], a0);
      a1 = fmaf(v, Wd[(size_t)(t + 256) * NLAT + ix], a1);
      a2 = fmaf(v, Wd[(size_t)(t + 512) * NLAT + ix], a2);
    }
  }
  float b0 = bvec[t], b1 = bvec[t + 256], b2 = bvec[t + 512];
  xhat[(size_t)r * NIN + t] = o0 + b0;
  xhat[(size_t)r * NIN + t + 256] = o1 + b1;
  xhat[(size_t)r * NIN + t + 512] = o2 + b2;
  auxo[(size_t)r * NIN + t] = a0 + b0;
  auxo[(size_t)r * NIN + t + 256] = a1 + b1;
  auxo[(size_t)r * NIN + t + 512] = a2 + b2;
}

extern "C" void kernel_launch(void* const* d_in, const int* in_sizes, int n_in,
                              void* d_out, int out_size, void* d_ws, size_t ws_size,
                              hipStream_t stream) {
  const float* x  = (const float*)d_in[0];
  const float* bv = (const float*)d_in[1];
  const float* We = (const float*)d_in[2];
  const float* be = (const float*)d_in[3];
  const float* Wd = (const float*)d_in[4];
  const int* miss = (const int*)d_in[5];
  const int* kp   = (const int*)d_in[6];
  const int* akp  = (const int*)d_in[7];

  float* out   = (float*)d_out;
  float* xhat  = out;                          // [4096 x 768]
  float* alpha = out + (size_t)3145728;        // [4096 x 24576]
  float* apre  = out + (size_t)103809024;      // fired_mask region; alpha_pre scratch
  float* auxo  = out + (size_t)204472320;      // [4096 x 768]

  // ws layout: deadbits (64K pad) | Wt bf16 (36M) | A2 (12M) | B2 (72M)
  unsigned* dbits = (unsigned*)d_ws;
  size_t offWt = 65536;
  size_t offA2 = offWt + (size_t)NLAT * NIN * 2;
  size_t offB2 = offA2 + (size_t)NB * K2 * 2;
  size_t needFull = offB2 + (size_t)NLAT * K2 * 2;
  bool haveWt   = ws_size >= offA2;
  bool haveFull = ws_size >= needFull;
  __bf16* Wt = haveWt ? (__bf16*)((char*)d_ws + offWt) : nullptr;
  __bf16* A2 = (__bf16*)((char*)d_ws + offA2);
  __bf16* B2 = (__bf16*)((char*)d_ws + offB2);

  k_deadbits<<<96, 256, 0, stream>>>(miss, dbits);
  if (haveFull) {
    k_pack_a<<<dim3(32, KT2), 256, 0, stream>>>(x, bv, A2);
    k_pack_b<<<dim3(192, KT2), 256, 0, stream>>>(We, B2);
  }
  if (haveWt)
    k_transpose<<<dim3(NLAT / 32, NIN / 32), dim3(32, 8), 0, stream>>>(Wd, Wt);

  if (haveFull)
    k_gemm_bf16<<<dim3(32, 192), 256, 0, stream>>>(A2, B2, be, apre);
  else
    k_encgemm_f32<<<dim3(NB / BM, NLAT / BN), 256, 0, stream>>>(x, bv, We, be, apre);

  k_select2<<<NB, 256, 0, stream>>>(apre, x, bv, We, be, dbits, kp, akp,
                                    alpha, apre, xhat, auxo, Wt, Wd);
}

// Round 4
// 3544.637 us; speedup vs baseline: 1.1192x; 1.1192x over previous
//
#include <hip/hip_runtime.h>
#include <math.h>

#define NB   4096
#define NIN  768
#define NLAT 24576
#define K2   1536   // [Ah|Al] x [Bh|Bh]
#define KT2  24     // K2/64

// f32 fallback GEMM tiling
#define BM 128
#define BN 128
#define BK 16
#define LDT 132

#define CAND_CAP 160
#define BAND_CAP 160
#define MAIN_CAP 64
#define AUX_CAP  1024
#define SELT     1024
#define EPT      24     // elements per thread = NLAT/SELT
#define GRP      6      // float4 groups per thread

typedef __bf16 bf16x8 __attribute__((ext_vector_type(8)));
typedef float  f32x4  __attribute__((ext_vector_type(4)));

__device__ __forceinline__ unsigned fkey(float f) {
  unsigned u = __float_as_uint(f);
  return u ^ ((unsigned)((int)u >> 31) | 0x80000000u);  // monotone total order
}
__device__ __forceinline__ float keyinv(unsigned u) {
  unsigned s = (u & 0x80000000u) ? (u ^ 0x80000000u) : ~u;
  return __uint_as_float(s);
}

#define GLOAD16(g, l) __builtin_amdgcn_global_load_lds( \
    (const __attribute__((address_space(1))) unsigned int*)(g), \
    (__attribute__((address_space(3))) unsigned int*)(l), 16, 0, 0)

// ---------------- dead bitset: bit j = (miss[j] >= 1) ----------------
__global__ __launch_bounds__(256) void k_deadbits(const int* __restrict__ miss,
                                                  unsigned* __restrict__ bits) {
  int j = blockIdx.x * 256 + threadIdx.x;
  unsigned long long b = __ballot(miss[j] >= 1);
  if ((threadIdx.x & 63) == 0) {
    int w = j >> 5;
    bits[w] = (unsigned)b;
    bits[w + 1] = (unsigned)(b >> 32);
  }
}

// ---------------- W_dec [NIN][NLAT] -> Wt [NLAT][NIN] (bf16) ----------------
__global__ __launch_bounds__(256) void k_transpose(const float* __restrict__ src,
                                                   __bf16* __restrict__ dst) {
  __shared__ float tile[32][33];
  int bx = blockIdx.x * 32;  // NLAT
  int by = blockIdx.y * 32;  // NIN
  int tx = threadIdx.x, ty = threadIdx.y;
  for (int i = ty; i < 32; i += 8)
    tile[i][tx] = src[(size_t)(by + i) * NLAT + bx + tx];
  __syncthreads();
  for (int i = ty; i < 32; i += 8)
    dst[(size_t)(bx + i) * NIN + by + tx] = (__bf16)tile[tx][i];
}

// ---- pack (x-b) into A2 tiles [mt][kt][128][64], pre-swizzled LDS image ----
__global__ __launch_bounds__(256) void k_pack_a(const float* __restrict__ x,
    const float* __restrict__ bvec, __bf16* __restrict__ A2) {
  const int mt = blockIdx.x, kt = blockIdx.y, t = threadIdx.x;
  __bf16* out = A2 + (((size_t)mt * KT2 + kt) << 13);
#pragma unroll
  for (int i = 0; i < 32; ++i) {
    int idx = i * 256 + t;
    int r = idx >> 6, c2 = idx & 63;
    int kk = c2 ^ ((r & 7) << 3);
    int kg = kt * 64 + kk;
    int k = kg >= 768 ? kg - 768 : kg;
    bool lo = (kg >= 768);                            // A = [Ah | Al]
    float v = x[(size_t)(mt * 128 + r) * NIN + k] - bvec[k];
    __bf16 h = (__bf16)v;
    out[idx] = lo ? (__bf16)(v - (float)h) : h;
  }
}

__global__ __launch_bounds__(256) void k_pack_b(const float* __restrict__ We,
    __bf16* __restrict__ B2) {
  const int nt = blockIdx.x, kt = blockIdx.y, t = threadIdx.x;
  __bf16* out = B2 + (((size_t)nt * KT2 + kt) << 13);
#pragma unroll
  for (int i = 0; i < 32; ++i) {
    int idx = i * 256 + t;
    int r = idx >> 6, c2 = idx & 63;
    int kk = c2 ^ ((r & 7) << 3);
    int kg = kt * 64 + kk;
    int k = kg >= 768 ? kg - 768 : kg;                // B = [Bh | Bh]
    float v = We[(size_t)(nt * 128 + r) * NIN + k];
    out[idx] = (__bf16)v;
  }
}

// ---------------- bf16 MFMA GEMM: apre = A2 @ B2^T + be ----------------
__global__ __launch_bounds__(256) void k_gemm_bf16(
    const __bf16* __restrict__ A2, const __bf16* __restrict__ B2,
    const float* __restrict__ be, float* __restrict__ apre) {
  __shared__ char sA[16384];
  __shared__ char sB[16384];
  const int t = threadIdx.x;
  const int lane = t & 63, wave = t >> 6;
  const int mt = blockIdx.x, nt = blockIdx.y;
  const int wm = wave >> 1, wn = wave & 1;

  int aoff[4][2], boff[4][2];
#pragma unroll
  for (int f = 0; f < 4; ++f) {
    int ra = wm * 64 + f * 16 + (lane & 15);
    int rb = wn * 64 + f * 16 + (lane & 15);
#pragma unroll
    for (int kk = 0; kk < 2; ++kk) {
      int c = kk * 64 + (lane >> 4) * 16;
      aoff[f][kk] = ra * 128 + (c ^ ((ra & 7) << 4));
      boff[f][kk] = rb * 128 + (c ^ ((rb & 7) << 4));
    }
  }
  f32x4 acc[4][4] = {};
  const char* gA = (const char*)(A2 + (((size_t)mt * KT2) << 13));
  const char* gB = (const char*)(B2 + (((size_t)nt * KT2) << 13));
  for (int kt = 0; kt < KT2; ++kt) {
    const char* tA = gA + ((size_t)kt << 14);
    const char* tB = gB + ((size_t)kt << 14);
#pragma unroll
    for (int i = 0; i < 4; ++i) {
      int chunk = (i * 4 + wave) * 1024;
      GLOAD16(tA + chunk + lane * 16, sA + chunk);
      GLOAD16(tB + chunk + lane * 16, sB + chunk);
    }
    __syncthreads();
#pragma unroll
    for (int kk = 0; kk < 2; ++kk) {
      bf16x8 a[4], b[4];
#pragma unroll
      for (int f = 0; f < 4; ++f) {
        a[f] = *(const bf16x8*)(sA + aoff[f][kk]);
        b[f] = *(const bf16x8*)(sB + boff[f][kk]);
      }
#pragma unroll
      for (int mi = 0; mi < 4; ++mi)
#pragma unroll
        for (int ni = 0; ni < 4; ++ni)
          acc[mi][ni] = __builtin_amdgcn_mfma_f32_16x16x32_bf16(a[mi], b[ni], acc[mi][ni], 0, 0, 0);
    }
    __syncthreads();
  }
  const int m0 = mt * 128 + wm * 64, n0 = nt * 128 + wn * 64;
#pragma unroll
  for (int ni = 0; ni < 4; ++ni) {
    int n = n0 + ni * 16 + (lane & 15);
    float bb = be[n];
#pragma unroll
    for (int mi = 0; mi < 4; ++mi) {
      int mbase = m0 + mi * 16 + (lane >> 4) * 4;
#pragma unroll
      for (int q = 0; q < 4; ++q)
        apre[(size_t)(mbase + q) * NLAT + n] = acc[mi][ni][q] + bb;
    }
  }
}

// ---------------- f32 fallback GEMM ----------------
__global__ __launch_bounds__(256) void k_encgemm_f32(
    const float* __restrict__ x, const float* __restrict__ bvec,
    const float* __restrict__ We, const float* __restrict__ be,
    float* __restrict__ apre) {
  __shared__ float As[BK][LDT];
  __shared__ float Bs[BK][LDT];
  const int t = threadIdx.x;
  const int m0 = blockIdx.x * BM;
  const int n0 = blockIdx.y * BN;
  const int lane = t & 63, wave = t >> 6;
  const int cn = ((wave & 1) * 8 + (lane & 7)) * 8;
  const int cm = ((wave >> 1) * 8 + (lane >> 3)) * 8;
  float acc[8][8] = {};
  const float* xb = x + (size_t)m0 * NIN;
  const float* wb = We + (size_t)n0 * NIN;
  for (int k0 = 0; k0 < NIN; k0 += BK) {
#pragma unroll
    for (int i = 0; i < 2; ++i) {
      int e = t + i * 256;
      int row = e >> 2, q = e & 3;
      float4 bv = *(const float4*)(bvec + k0 + q * 4);
      float4 av = *(const float4*)(xb + (size_t)row * NIN + k0 + q * 4);
      av.x -= bv.x; av.y -= bv.y; av.z -= bv.z; av.w -= bv.w;
      As[q * 4 + 0][row] = av.x; As[q * 4 + 1][row] = av.y;
      As[q * 4 + 2][row] = av.z; As[q * 4 + 3][row] = av.w;
      float4 wv = *(const float4*)(wb + (size_t)row * NIN + k0 + q * 4);
      Bs[q * 4 + 0][row] = wv.x; Bs[q * 4 + 1][row] = wv.y;
      Bs[q * 4 + 2][row] = wv.z; Bs[q * 4 + 3][row] = wv.w;
    }
    __syncthreads();
#pragma unroll
    for (int kk = 0; kk < BK; ++kk) {
      float a0[8], b0[8];
      *(float4*)&a0[0] = *(const float4*)&As[kk][cm];
      *(float4*)&a0[4] = *(const float4*)&As[kk][cm + 4];
      *(float4*)&b0[0] = *(const float4*)&Bs[kk][cn];
      *(float4*)&b0[4] = *(const float4*)&Bs[kk][cn + 4];
#pragma unroll
      for (int i = 0; i < 8; ++i)
#pragma unroll
        for (int j = 0; j < 8; ++j)
          acc[i][j] = fmaf(a0[i], b0[j], acc[i][j]);
    }
    __syncthreads();
  }
  float bb[8];
  *(float4*)&bb[0] = *(const float4*)(be + n0 + cn);
  *(float4*)&bb[4] = *(const float4*)(be + n0 + cn + 4);
#pragma unroll
  for (int i = 0; i < 8; ++i) {
    float4 v0 = make_float4(acc[i][0] + bb[0], acc[i][1] + bb[1],
                            acc[i][2] + bb[2], acc[i][3] + bb[3]);
    float4 v1 = make_float4(acc[i][4] + bb[4], acc[i][5] + bb[5],
                            acc[i][6] + bb[6], acc[i][7] + bb[7]);
    float* orow = apre + (size_t)(m0 + cm + i) * NLAT + n0 + cn;
    *(float4*)orow = v0;
    *(float4*)(orow + 4) = v1;
  }
}

// ------------- per-row: 1024-thread register-resident bisection top-k ----
// apre and mask alias — no __restrict__ on either; each block owns its row.
__global__ __launch_bounds__(SELT) void k_select3(
    const float* apre, const float* __restrict__ x,
    const float* __restrict__ bvec, const float* __restrict__ We,
    const float* __restrict__ be, const unsigned* __restrict__ dbits,
    const int* __restrict__ kptr, const int* __restrict__ akptr,
    float* __restrict__ alpha, float* mask,
    float* __restrict__ xhat, float* __restrict__ auxo,
    const __bf16* __restrict__ Wt, const float* __restrict__ Wd) {
  const int t = threadIdx.x;
  const int r = blockIdx.x;
  const int lane = t & 63, wave = t >> 6;   // 16 waves

  __shared__ int wred[2][16];
  __shared__ unsigned wredu[2][16];
  __shared__ int ctrl[8];
  __shared__ unsigned candK[CAND_CAP];
  __shared__ int candI[CAND_CAP];
  __shared__ int bandI[BAND_CAP];
  __shared__ double bandV[BAND_CAP];
  __shared__ unsigned char bandSel[BAND_CAP];
  __shared__ int mIdx[MAIN_CAP];
  __shared__ float mVal[MAIN_CAP];
  __shared__ int aIdx[AUX_CAP];
  __shared__ float aVal[AUX_CAP];

  // ---- load row as sort keys (24 regs) + dead bits (1 reg) ----
  unsigned key[EPT];
  const float4* rowp = (const float4*)(apre + (size_t)r * NLAT);
  unsigned dm = 0;
#pragma unroll
  for (int i = 0; i < GRP; ++i) {
    int g = t + SELT * i;
    float4 v = rowp[g];
    key[4 * i + 0] = fkey(v.x); key[4 * i + 1] = fkey(v.y);
    key[4 * i + 2] = fkey(v.z); key[4 * i + 3] = fkey(v.w);
    unsigned nb = (dbits[g >> 3] >> ((g & 7) * 4)) & 0xFu;
    dm |= nb << (4 * i);
  }
  int kmain = kptr[0]; if (kmain > MAIN_CAP) kmain = MAIN_CAP;
  int kaux  = akptr[0]; if (kaux > AUX_CAP)  kaux  = AUX_CAP;

  int par = 0, paru = 0;
  int kcMain = 0, acAux = 0;
  unsigned KhiB = 0, KloB = 0;
  int bcKeep = 0;

  for (int pass = 0; pass < 2; ++pass) {
    int kreq, nelig;
    if (pass == 0) { kreq = kmain; nelig = NLAT; }
    else {
      // marker 0u (< any finite key 0x00800000) for non-dead latents
#pragma unroll
      for (int e = 0; e < EPT; ++e)
        if (!((dm >> e) & 1u)) key[e] = 0u;
      int pc = __popc(dm & 0xFFFFFFu);
#pragma unroll
      for (int o = 32; o; o >>= 1) pc += __shfl_xor(pc, o);
      if (lane == 0) wred[par][wave] = pc;
      __syncthreads();
      nelig = 0;
#pragma unroll
      for (int w = 0; w < 16; ++w) nelig += wred[par][w];
      par ^= 1;
      kreq = kaux;
    }
    if (kreq > nelig) kreq = nelig;
    if (kreq <= 0) { if (pass == 1) acAux = 0; continue; }

    // ---- block max/min of eligible keys (markers excluded via 0/UINT_MAX) ----
    unsigned mx = 0u, mn = 0xFFFFFFFFu;
#pragma unroll
    for (int e = 0; e < EPT; ++e) {
      unsigned kk = key[e];
      bool el = (pass == 0) || ((dm >> e) & 1u);
      if (el) { mx = kk > mx ? kk : mx; mn = kk < mn ? kk : mn; }
    }
#pragma unroll
    for (int o = 32; o; o >>= 1) {
      unsigned om = __shfl_xor(mx, o); mx = om > mx ? om : mx;
      unsigned on = __shfl_xor(mn, o); mn = on < mn ? on : mn;
    }
    if (lane == 0) { wredu[paru][wave] = mx; wredu[paru ^ 1][wave] = mn; }
    __syncthreads();
    mx = 0u; mn = 0xFFFFFFFFu;
#pragma unroll
    for (int w = 0; w < 16; ++w) {
      unsigned a = wredu[paru][w], b = wredu[paru ^ 1][w];
      mx = a > mx ? a : mx; mn = b < mn ? b : mn;
    }
    __syncthreads();  // wredu reused next pass; full drain (rare, cheap)

    // ---- value-space bisection for the k-th boundary window ----
    unsigned Tlo = mn, Thi = mx + 1u;
    int cLo = nelig, cHi = 0;
    float vlo = keyinv(mn), vhi = keyinv(mx);
    for (int it = 0; it < 48 && (cLo - cHi) > (CAND_CAP - 8); ++it) {
      float vm = 0.5f * vlo + 0.5f * vhi;
      unsigned T = fkey(vm);
      if (!(T > Tlo && T < Thi)) break;
      int c = 0;
#pragma unroll
      for (int e = 0; e < EPT; ++e) c += (key[e] >= T) ? 1 : 0;
#pragma unroll
      for (int o = 32; o; o >>= 1) c += __shfl_xor(c, o);
      if (lane == 0) wred[par][wave] = c;
      __syncthreads();
      c = 0;
#pragma unroll
      for (int w = 0; w < 16; ++w) c += wred[par][w];
      par ^= 1;
      if (c >= kreq) { Tlo = T; cLo = c; vlo = vm; }
      else           { Thi = T; cHi = c; vhi = vm; }
    }

    // ---- extract window candidates, exact-rank the k-th key ----
    if (t == 0) ctrl[0] = 0;
    __syncthreads();
#pragma unroll
    for (int i = 0; i < GRP; ++i)
#pragma unroll
      for (int q = 0; q < 4; ++q) {
        unsigned kk = key[4 * i + q];
        if (kk >= Tlo && kk < Thi) {
          int p = atomicAdd(&ctrl[0], 1);
          if (p < CAND_CAP) { candK[p] = kk; candI[p] = 4 * (t + SELT * i) + q; }
        }
      }
    __syncthreads();
    int cc = ctrl[0]; if (cc > CAND_CAP) cc = CAND_CAP;
    int need = kreq - cHi;
    if (need < 1) need = 1;
    if (need > cc) need = cc;
    if (t < cc) {
      unsigned ki = candK[t]; int ii = candI[t];
      int rank = 0;
      for (int qq = 0; qq < cc; ++qq) {
        unsigned kq = candK[qq];
        rank += (kq > ki || (kq == ki && candI[qq] < ii)) ? 1 : 0;
      }
      if (rank == need - 1) ctrl[1] = (int)ki;
    }
    __syncthreads();

    // ---- f64 band refinement around V* ----
    float Vs = keyinv((unsigned)ctrl[1]);
    float eps = 1e-2f + 2e-3f * fabsf(Vs);
    KhiB = fkey(Vs + eps); KloB = fkey(Vs - eps);
    if (t == 0) { ctrl[2] = 0; ctrl[3] = 0; }
    __syncthreads();
    int abv = 0;
#pragma unroll
    for (int i = 0; i < GRP; ++i)
#pragma unroll
      for (int q = 0; q < 4; ++q) {
        unsigned kk = key[4 * i + q];
        if (kk > KhiB) ++abv;
        else if (kk >= KloB) {
          int p = atomicAdd(&ctrl[3], 1);
          if (p < BAND_CAP) bandI[p] = 4 * (t + SELT * i) + q;
        }
      }
#pragma unroll
    for (int o = 32; o; o >>= 1) abv += __shfl_xor(abv, o);
    if (lane == 0) atomicAdd(&ctrl[2], abv);
    __syncthreads();
    int nAb = ctrl[2];
    int bc = ctrl[3]; if (bc > BAND_CAP) bc = BAND_CAP;
    bcKeep = bc;
    int needB = kreq - nAb;
    if (needB < 0) needB = 0;
    if (needB > bc) needB = bc;

    if (t < bc) {
      int j = bandI[t];
      const float* wr = We + (size_t)j * NIN;
      const float* xr = x + (size_t)r * NIN;
      double s0 = 0.0, s1 = 0.0, s2 = 0.0, s3 = 0.0;
      for (int kx = 0; kx < NIN; kx += 4) {
        s0 += ((double)xr[kx]     - (double)bvec[kx])     * (double)wr[kx];
        s1 += ((double)xr[kx + 1] - (double)bvec[kx + 1]) * (double)wr[kx + 1];
        s2 += ((double)xr[kx + 2] - (double)bvec[kx + 2]) * (double)wr[kx + 2];
        s3 += ((double)xr[kx + 3] - (double)bvec[kx + 3]) * (double)wr[kx + 3];
      }
      bandV[t] = ((s0 + s1) + (s2 + s3)) + (double)be[j];
    }
    __syncthreads();
    if (t < bc) {
      double vi = bandV[t]; int ii = bandI[t];
      double tie = fabs(vi) * 4e-8 + 1e-12;
      int rank = 0;
      for (int qq = 0; qq < bc; ++qq) {
        double d = bandV[qq] - vi;
        rank += ((fabs(d) <= tie) ? (bandI[qq] < ii) : (d > 0.0)) ? 1 : 0;
      }
      bandSel[t] = (rank < needB) ? 1 : 0;
    }
    if (t == 0) ctrl[4] = 0;
    __syncthreads();

    // ---- emit ----
    if (pass == 0) {
      float4* arow = (float4*)(alpha + (size_t)r * NLAT);
      float4* mrow = (float4*)(mask + (size_t)r * NLAT);
#pragma unroll
      for (int i = 0; i < GRP; ++i) {
        float av[4], mv[4];
#pragma unroll
        for (int q = 0; q < 4; ++q) {
          unsigned kk = key[4 * i + q];
          int j = 4 * (t + SELT * i) + q;
          bool sel = kk > KhiB;
          if (!sel && kk >= KloB) {
            for (int m2 = 0; m2 < bc; ++m2)
              if (bandI[m2] == j) { sel = bandSel[m2] != 0; break; }
          }
          float v = keyinv(kk);
          bool nz = sel && (v != 0.0f);
          av[q] = sel ? v : 0.0f;
          mv[q] = nz ? 1.0f : 0.0f;
          if (nz) {
            int p = atomicAdd(&ctrl[4], 1);
            if (p < MAIN_CAP) { mIdx[p] = j; mVal[p] = v; }
          }
        }
        arow[t + SELT * i] = make_float4(av[0], av[1], av[2], av[3]);
        mrow[t + SELT * i] = make_float4(mv[0], mv[1], mv[2], mv[3]);
      }
    } else {
#pragma unroll
      for (int i = 0; i < GRP; ++i)
#pragma unroll
        for (int q = 0; q < 4; ++q) {
          unsigned kk = key[4 * i + q];
          if (kk == 0u) continue;  // marker (non-dead)
          int j = 4 * (t + SELT * i) + q;
          bool sel = kk > KhiB;
          if (!sel && kk >= KloB) {
            for (int m2 = 0; m2 < bc; ++m2)
              if (bandI[m2] == j) { sel = bandSel[m2] != 0; break; }
          }
          float v = keyinv(kk);
          if (sel && v != 0.0f) {
            int p = atomicAdd(&ctrl[4], 1);
            if (p < AUX_CAP) { aIdx[p] = j; aVal[p] = v; }
          }
        }
    }
    __syncthreads();
    if (pass == 0) kcMain = ctrl[4] < MAIN_CAP ? ctrl[4] : MAIN_CAP;
    else           acAux  = ctrl[4] < AUX_CAP  ? ctrl[4] : AUX_CAP;
    __syncthreads();
  }

  // ---- decode (threads 0..767): xhat = sum mVal*Wdec[:,mIdx] + b ----
  if (t < NIN) {
    int kc = kcMain, ac = acAux;
    float o0 = 0.f, a0 = 0.f, a1 = 0.f;
    if (Wt) {
      for (int i = 0; i < kc; ++i)
        o0 = fmaf(mVal[i], (float)Wt[(size_t)mIdx[i] * NIN + t], o0);
      int i = 0;
      for (; i + 1 < ac; i += 2) {
        a0 = fmaf(aVal[i],     (float)Wt[(size_t)aIdx[i]     * NIN + t], a0);
        a1 = fmaf(aVal[i + 1], (float)Wt[(size_t)aIdx[i + 1] * NIN + t], a1);
      }
      if (i < ac) a0 = fmaf(aVal[i], (float)Wt[(size_t)aIdx[i] * NIN + t], a0);
    } else {
      for (int i = 0; i < kc; ++i)
        o0 = fmaf(mVal[i], Wd[(size_t)t * NLAT + mIdx[i]], o0);
      for (int i = 0; i < ac; ++i)
        a0 = fmaf(aVal[i], Wd[(size_t)t * NLAT + aIdx[i]], a0);
    }
    float bb = bvec[t];
    xhat[(size_t)r * NIN + t] = o0 + bb;
    auxo[(size_t)r * NIN + t] = (a0 + a1) + bb;
  }
}

extern "C" void kernel_launch(void* const* d_in, const int* in_sizes, int n_in,
                              void* d_out, int out_size, void* d_ws, size_t ws_size,
                              hipStream_t stream) {
  const float* x  = (const float*)d_in[0];
  const float* bv = (const float*)d_in[1];
  const float* We = (const float*)d_in[2];
  const float* be = (const float*)d_in[3];
  const float* Wd = (const float*)d_in[4];
  const int* miss = (const int*)d_in[5];
  const int* kp   = (const int*)d_in[6];
  const int* akp  = (const int*)d_in[7];

  float* out   = (float*)d_out;
  float* xhat  = out;                          // [4096 x 768]
  float* alpha = out + (size_t)3145728;        // [4096 x 24576]
  float* apre  = out + (size_t)103809024;      // fired_mask region; alpha_pre scratch
  float* auxo  = out + (size_t)204472320;      // [4096 x 768]

  // ws layout: deadbits (64K pad) | Wt bf16 (36M) | A2 (12M) | B2 (72M)
  unsigned* dbits = (unsigned*)d_ws;
  size_t offWt = 65536;
  size_t offA2 = offWt + (size_t)NLAT * NIN * 2;
  size_t offB2 = offA2 + (size_t)NB * K2 * 2;
  size_t needFull = offB2 + (size_t)NLAT * K2 * 2;
  bool haveWt   = ws_size >= offA2;
  bool haveFull = ws_size >= needFull;
  __bf16* Wt = haveWt ? (__bf16*)((char*)d_ws + offWt) : nullptr;
  __bf16* A2 = (__bf16*)((char*)d_ws + offA2);
  __bf16* B2 = (__bf16*)((char*)d_ws + offB2);

  k_deadbits<<<96, 256, 0, stream>>>(miss, dbits);
  if (haveFull) {
    k_pack_a<<<dim3(32, KT2), 256, 0, stream>>>(x, bv, A2);
    k_pack_b<<<dim3(192, KT2), 256, 0, stream>>>(We, B2);
  }
  if (haveWt)
    k_transpose<<<dim3(NLAT / 32, NIN / 32), dim3(32, 8), 0, stream>>>(Wd, Wt);

  if (haveFull)
    k_gemm_bf16<<<dim3(32, 192), 256, 0, stream>>>(A2, B2, be, apre);
  else
    k_encgemm_f32<<<dim3(NB / BM, NLAT / BN), 256, 0, stream>>>(x, bv, We, be, apre);

  k_select3<<<NB, SELT, 0, stream>>>(apre, x, bv, We, be, dbits, kp, akp,
                                     alpha, apre, xhat, auxo, Wt, Wd);
}